// Round 2
// baseline (169.132 us; speedup 1.0000x reference)
//
#include <hip/hip_runtime.h>

#define IN_C 192
#define HW   9600   // 80*120
#define NPIX 128

typedef __attribute__((ext_vector_type(8))) short bf16x8;
typedef __attribute__((ext_vector_type(4))) float f32x4;

static __device__ __forceinline__ short f2bf(float f) {
  // round-to-nearest-even fp32 -> bf16 (inputs are finite normals)
  unsigned u = __builtin_bit_cast(unsigned, f);
  u += 0x7FFFu + ((u >> 16) & 1u);
  return (short)(u >> 16);
}

// Pack W (192x192 fp32, row-major [o][k]) into fragment-sequential bf16:
// frag (mo, kk): 64 lanes x 8 bf16 (16B/lane), lane l -> o = mo*16 + (l&15),
// k = kk*32 + (l>>4)*8 + j. Same k(l,j) convention as the x B-frags, so any
// true intra-fragment k-permutation of the HW layout cancels (validated R1).
__global__ void pack_w_kernel(const float* __restrict__ W, short* __restrict__ wp) {
  int idx = blockIdx.x * 256 + threadIdx.x;   // 0 .. 12*6*64-1 = 4607
  if (idx >= 12 * 6 * 64) return;
  int mo  = idx / (6 * 64);
  int rem = idx % (6 * 64);
  int kk  = rem / 64;
  int l   = rem % 64;
  int o   = mo * 16 + (l & 15);
  int kb  = kk * 32 + (l >> 4) * 8;
  bf16x8 v;
#pragma unroll
  for (int j = 0; j < 8; ++j) v[j] = f2bf(W[o * IN_C + kb + j]);
  *reinterpret_cast<bf16x8*>(wp + (size_t)idx * 8) = v;
}

// Per-pixel GEMM D[o][p] = sum_k W[o][k]*x[b][k][p] + bias[o], sub-block scatter.
// x tile staged async global->LDS (fp32 [32k][128px], XOR-swizzled px by g=k>>3),
// double-buffered: stage(kk+1) overlaps compute(kk); one __syncthreads per step
// (its implicit vmcnt(0)+lgkmcnt(0) drain is the per-tile wait).
__global__ __launch_bounds__(256, 4) void conv_mfma_kernel(
    const float* __restrict__ x, const short* __restrict__ wp,
    const float* __restrict__ bias, float* __restrict__ out) {
  __shared__ float sx[2][32 * 128];   // 2 x 16 KB

  const int tid  = threadIdx.x;
  const int wid  = tid >> 6;
  const int lane = tid & 63;
  const int c    = lane & 15;
  const int g    = lane >> 4;
  const int b    = blockIdx.y;
  const int ptile = blockIdx.x * NPIX;

  const float* xb = x + (size_t)b * IN_C * HW + ptile;

  // Staging geometry: 16 wave-insts per 32x128 tile; inst t (= wid*4 + r)
  // covers k-rows {2t, 2t+1} (1024 B of LDS, linear dest = base + lane*16).
  // lane l: k = 2t + (l>>5), dest words (l&31)*4..+3 -> swizzled q' chunk;
  // global source q = q' ^ s(k), s(k) = ((k>>3)&3)<<3 (4-chunk stays contiguous).
  const int krow = lane >> 5;
  const int mchunk = (lane & 31) * 4;

  f32x4 acc[12][2];
#pragma unroll
  for (int mo = 0; mo < 12; ++mo) {
    acc[mo][0] = (f32x4)0.0f;
    acc[mo][1] = (f32x4)0.0f;
  }

#define STAGE(BUF, KK)                                                          \
  {                                                                             \
    _Pragma("unroll")                                                           \
    for (int r = 0; r < 4; ++r) {                                               \
      const int t  = wid * 4 + r;                                               \
      const int kl = 2 * t + krow;                                              \
      const int qsrc = mchunk ^ (((kl >> 3) & 3) << 3);                         \
      const float* src = xb + (size_t)((KK) * 32 + kl) * HW + qsrc;             \
      float* dst = &sx[(BUF)][t * 256];                                         \
      __builtin_amdgcn_global_load_lds(                                         \
          (const __attribute__((address_space(1))) void*)src,                   \
          (__attribute__((address_space(3))) void*)dst, 16, 0, 0);              \
    }                                                                           \
  }

  STAGE(0, 0);
  __syncthreads();   // buf0 staged (drains vmcnt before barrier)

#pragma unroll
  for (int kk = 0; kk < 6; ++kk) {
    const int cur = kk & 1;
    if (kk < 5) STAGE(cur ^ 1, kk + 1);   // overlaps this step's compute

    // B-frags from LDS: lane needs x[k = g*8+j][q = wid*32+np*16+c],
    // stored at word k*128 + (q ^ (g<<3))  -> 2-way bank conflict (free).
    bf16x8 bfr[2];
#pragma unroll
    for (int np = 0; np < 2; ++np) {
      const int q  = wid * 32 + np * 16 + c;
      const int qs = q ^ (g << 3);
      bf16x8 v;
#pragma unroll
      for (int j = 0; j < 8; ++j) v[j] = f2bf(sx[cur][(g * 8 + j) * 128 + qs]);
      bfr[np] = v;
    }

    // A-frags: packed W from global (L2/L3-resident, 16B/lane coalesced)
#pragma unroll
    for (int mo = 0; mo < 12; ++mo) {
      const bf16x8 af = *reinterpret_cast<const bf16x8*>(
          wp + (size_t)(((mo * 6 + kk) * 64) + lane) * 8);
      acc[mo][0] = __builtin_amdgcn_mfma_f32_16x16x32_bf16(af, bfr[0], acc[mo][0], 0, 0, 0);
      acc[mo][1] = __builtin_amdgcn_mfma_f32_16x16x32_bf16(af, bfr[1], acc[mo][1], 0, 0, 0);
    }

    __syncthreads();   // stage(kk+1) landed + all reads of buf[cur] done
  }
#undef STAGE

  // Epilogue: C/D col = lane&15 (pixel), row = (lane>>4)*4 + r (out-ch).
  const int pwv = ptile + wid * 32;
#pragma unroll
  for (int np = 0; np < 2; ++np) {
    const int p  = pwv + np * 16 + c;
    const int hi = p / 120;
    const int wi = p - hi * 120;
#pragma unroll
    for (int mo = 0; mo < 12; ++mo) {
      const int ob = mo * 16 + g * 4;
      const f32x4 bv = *reinterpret_cast<const f32x4*>(bias + ob);
      const f32x4 v  = acc[mo][np];
#pragma unroll
      for (int r = 0; r < 4; ++r) {
        const int o  = ob + r;
        const int co = o >> 6;
        const int br = (o >> 3) & 7;
        const int bc = o & 7;
        const int idx = ((b * 3 + co) * 640 + br * 80 + hi) * 960 + bc * 120 + wi;
        out[idx] = v[r] + bv[r];
      }
    }
  }
}

extern "C" void kernel_launch(void* const* d_in, const int* in_sizes, int n_in,
                              void* d_out, int out_size, void* d_ws, size_t ws_size,
                              hipStream_t stream) {
  const float* x    = (const float*)d_in[0];
  const float* W    = (const float*)d_in[1];
  const float* bias = (const float*)d_in[2];
  float* out = (float*)d_out;
  short* wp  = (short*)d_ws;   // 192*192 bf16 packed-fragment W (73728 B)

  pack_w_kernel<<<18, 256, 0, stream>>>(W, wp);
  dim3 grid(75, 16);  // 75 pixel tiles of 128 (9600 exact), 16 batches
  conv_mfma_kernel<<<grid, 256, 0, stream>>>(x, wp, bias, out);
}

// Round 3
// 59.200 us; speedup vs baseline: 2.8570x; 2.8570x over previous
//
#include <hip/hip_runtime.h>

#define IN_C 192
#define HW   9600   // 80*120
#define NPIX 64     // pixels per block (4 waves x 16-px strips)

typedef __attribute__((ext_vector_type(8))) short bf16x8;
typedef __attribute__((ext_vector_type(4))) float f32x4;

static __device__ __forceinline__ short f2bf(float f) {
  // round-to-nearest-even fp32 -> bf16 (inputs are finite normals)
  unsigned u = __builtin_bit_cast(unsigned, f);
  u += 0x7FFFu + ((u >> 16) & 1u);
  return (short)(u >> 16);
}

// Pack W (192x192 fp32, row-major [o][k]) into fragment-sequential bf16:
// frag (mo, kk): 64 lanes x 8 bf16 (16B/lane), lane l -> o = mo*16 + (l&15),
// k = kk*32 + (l>>4)*8 + j. Same k(l,j) convention as the x B-frags, so any
// true intra-fragment k-permutation of the HW layout cancels (validated R1).
__global__ void pack_w_kernel(const float* __restrict__ W, short* __restrict__ wp) {
  int idx = blockIdx.x * 256 + threadIdx.x;   // 0 .. 12*6*64-1 = 4607
  if (idx >= 12 * 6 * 64) return;
  int mo  = idx / (6 * 64);
  int rem = idx % (6 * 64);
  int kk  = rem / 64;
  int l   = rem % 64;
  int o   = mo * 16 + (l & 15);
  int kb  = kk * 32 + (l >> 4) * 8;
  bf16x8 v;
#pragma unroll
  for (int j = 0; j < 8; ++j) v[j] = f2bf(W[o * IN_C + kb + j]);
  *reinterpret_cast<bf16x8*>(wp + (size_t)idx * 8) = v;
}

// Per-pixel GEMM D[o][p] = sum_k W[o][k]*x[b][k][p] + bias[o], sub-block scatter.
// No LDS, no barriers. Each wave owns a 16-px strip x all 192 out-ch:
// acc = 12 x f32x4 = 48 regs (half of R1 -> ~120 total unified regs -> 4 blk/CU).
// Depth-1 register prefetch of the next K-step's x values (named dbuf).
__global__ __launch_bounds__(256, 3) void conv_mfma_kernel(
    const float* __restrict__ x, const short* __restrict__ wp,
    const float* __restrict__ bias, float* __restrict__ out) {
  const int tid  = threadIdx.x;
  const int wid  = tid >> 6;
  const int lane = tid & 63;
  const int c    = lane & 15;
  const int g    = lane >> 4;
  const int b    = blockIdx.y;
  const int p    = blockIdx.x * NPIX + wid * 16 + c;   // this lane's pixel

  // lane's x column base: k = kk*32 + g*8 + j  ->  xp[(kk*32 + j)*HW]
  const float* xp = x + (size_t)b * IN_C * HW + (size_t)(g * 8) * HW + p;

  f32x4 acc[12];
#pragma unroll
  for (int mo = 0; mo < 12; ++mo) acc[mo] = (f32x4)0.0f;

  float xr0[8], xr1[8];

#define LOADX(DST, KK)                                                \
  { _Pragma("unroll")                                                 \
    for (int j = 0; j < 8; ++j)                                       \
      DST[j] = xp[(size_t)((KK) * 32 + j) * HW]; }

#define KSTEP(CURB, NXTB, KK)                                         \
  {                                                                   \
    if ((KK) < 5) { LOADX(NXTB, (KK) + 1); }                          \
    bf16x8 bfr;                                                       \
    _Pragma("unroll")                                                 \
    for (int j = 0; j < 8; ++j) bfr[j] = f2bf(CURB[j]);               \
    _Pragma("unroll")                                                 \
    for (int h = 0; h < 2; ++h) {                                     \
      bf16x8 af[6];                                                   \
      _Pragma("unroll")                                               \
      for (int m = 0; m < 6; ++m)                                     \
        af[m] = *reinterpret_cast<const bf16x8*>(                     \
            wp + (size_t)((((h * 6 + m) * 6 + (KK)) * 64) + lane) * 8); \
      _Pragma("unroll")                                               \
      for (int m = 0; m < 6; ++m)                                     \
        acc[h * 6 + m] = __builtin_amdgcn_mfma_f32_16x16x32_bf16(     \
            af[m], bfr, acc[h * 6 + m], 0, 0, 0);                     \
    }                                                                 \
  }

  LOADX(xr0, 0);
  KSTEP(xr0, xr1, 0);
  KSTEP(xr1, xr0, 1);
  KSTEP(xr0, xr1, 2);
  KSTEP(xr1, xr0, 3);
  KSTEP(xr0, xr1, 4);
  KSTEP(xr1, xr0, 5);
#undef KSTEP
#undef LOADX

  // Epilogue: C/D col = lane&15 (pixel, == c), row = g*4 + r (out-ch).
  const int hi = p / 120;
  const int wi = p - hi * 120;
#pragma unroll
  for (int mo = 0; mo < 12; ++mo) {
    const int ob = mo * 16 + g * 4;
    const f32x4 bv = *reinterpret_cast<const f32x4*>(bias + ob);
    const f32x4 v  = acc[mo];
#pragma unroll
    for (int r = 0; r < 4; ++r) {
      const int o  = ob + r;
      const int co = o >> 6;
      const int br = (o >> 3) & 7;
      const int bc = o & 7;
      const int idx = ((b * 3 + co) * 640 + br * 80 + hi) * 960 + bc * 120 + wi;
      out[idx] = v[r] + bv[r];
    }
  }
}

extern "C" void kernel_launch(void* const* d_in, const int* in_sizes, int n_in,
                              void* d_out, int out_size, void* d_ws, size_t ws_size,
                              hipStream_t stream) {
  const float* x    = (const float*)d_in[0];
  const float* W    = (const float*)d_in[1];
  const float* bias = (const float*)d_in[2];
  float* out = (float*)d_out;
  short* wp  = (short*)d_ws;   // 192*192 bf16 packed-fragment W (73728 B)

  pack_w_kernel<<<18, 256, 0, stream>>>(W, wp);
  dim3 grid(150, 16);  // 150 pixel tiles of 64 (9600 exact), 16 batches
  conv_mfma_kernel<<<grid, 256, 0, stream>>>(x, wp, bias, out);
}